// Round 10
// baseline (164.875 us; speedup 1.0000x reference)
//
#include <hip/hip_runtime.h>

// Problem constants (fixed by setup_inputs)
#define BB 4
#define CC 256
#define CQ 32
#define NN 4096   // H*W

// ws layout (bf16 element offsets)
#define QT_OFF 0
#define KT_OFF (BB*NN*CQ)                 //  524288
#define VT_OFF (2*BB*NN*CQ)               // 1048576 : tiled V, BB*64*16*1024
#define WB_OFF (VT_OFF + BB*CC*NN)        // 5242880 : bf16 W [320][256]
#define BIAS_OFF (WB_OFF + 320*256)       // 5324800 : fp32 bias[320] (16B-aligned)

// Barrier with LDS-only drain: does NOT wait vmcnt, so register prefetch
// loads (V/K fragments) stay in flight across the barrier. __syncthreads()
// would emit s_waitcnt vmcnt(0) and serialize every iteration on L2 latency.
#define LDS_BARRIER() asm volatile("s_waitcnt lgkmcnt(0)\ns_barrier" ::: "memory")

typedef __attribute__((ext_vector_type(8))) short bf16x8;
typedef __attribute__((ext_vector_type(4))) short bf16x4;
typedef __attribute__((ext_vector_type(4))) float f32x4;

__device__ inline unsigned short f2bf(float f) {
    unsigned int u = __float_as_uint(f);
    u += 0x7fffu + ((u >> 16) & 1u);   // round-to-nearest-even
    return (unsigned short)(u >> 16);
}

// ---------------------------------------------------------------------------
// prepW: pack wq/wk/wv into bf16 Wb[320][256] (rows 0-31 q, 32-63 k, 64-319 v)
// and biases into fp32 Bias[320]. Grid 320 x 256.  (R4-exact)
// ---------------------------------------------------------------------------
__global__ __launch_bounds__(256) void prepw_kernel(
    const float* __restrict__ wq, const float* __restrict__ bq,
    const float* __restrict__ wk, const float* __restrict__ bk,
    const float* __restrict__ wv, const float* __restrict__ bv,
    unsigned short* __restrict__ ws)
{
    unsigned short* Wb = ws + WB_OFF;
    float* Bias = (float*)(ws + BIAS_OFF);
    int idx = blockIdx.x * 256 + threadIdx.x;
    if (idx < 320 * 256) {
        int row = idx >> 8, col = idx & 255;
        float v = row < 32 ? wq[row * 256 + col]
                : row < 64 ? wk[(row - 32) * 256 + col]
                           : wv[(row - 64) * 256 + col];
        Wb[idx] = f2bf(v);
    }
    if (idx < 320)
        Bias[idx] = idx < 32 ? bq[idx] : idx < 64 ? bk[idx - 32] : bv[idx - 64];
}

// ---------------------------------------------------------------------------
// Fused x-transpose + QKV MFMA GEMM: [320 oc] x [256 c] x [32 pos].
// Grid (N/32, B) = 512 blocks (2/CU), 256 thr = 4 waves.  (R4-exact; the
// R9 512-thr variant regressed wall by a REAL +9.5 us -> reverted.)
// R10 MEASUREMENT ROUND: this kernel is launched 3x (idempotent -- writes
// qT/kT/vT deterministically from unchanged x/Wb), so wall = R4wall + 2*qkv
// with +-0.1 us precision on both terms. Resolves whether qkv is ~5 us
// (roofline) or ~25-35 us (the R8/R9 evidence) before any rewrite.
// ---------------------------------------------------------------------------
__global__ __launch_bounds__(256, 2) void qkv_kernel(
    const float* __restrict__ x, unsigned short* __restrict__ ws)
{
    __shared__ __align__(16) unsigned short xs[32][264];   // [pos][ch^swz]
    __shared__ __align__(16) unsigned short vs[256][40];   // [ch][pos]
    const int t = threadIdx.x;
    const int w = t >> 6, l = t & 63, quad = l >> 4, lc = l & 15;
    const int b = blockIdx.y, n0 = blockIdx.x * 32;

    unsigned short* qT = ws + QT_OFF;
    unsigned short* kT = ws + KT_OFF;
    const unsigned short* Wb = ws + WB_OFF;
    const float* Bias = (const float*)(ws + BIAS_OFF);

    // stage x tile: fp32 [256 ch][32 pos] -> bf16 xs[pos][ch ^ swz]
    const float* xb = x + (size_t)(b * CC) * NN + n0;
    {
        const int nq = t & 7, swz = (nq & 3) << 3;
#pragma unroll
        for (int u = 0; u < 2; ++u) {
            const int c0 = (t >> 3) * 4 + u * 128;
            f32x4 r0 = *(const f32x4*)&xb[(size_t)(c0 + 0) * NN + nq * 4];
            f32x4 r1 = *(const f32x4*)&xb[(size_t)(c0 + 1) * NN + nq * 4];
            f32x4 r2 = *(const f32x4*)&xb[(size_t)(c0 + 2) * NN + nq * 4];
            f32x4 r3 = *(const f32x4*)&xb[(size_t)(c0 + 3) * NN + nq * 4];
            const int cs = c0 ^ swz;   // c0 mult of 4, swz bits 3-4 -> 8B aligned
#pragma unroll
            for (int k = 0; k < 4; ++k) {
                bf16x4 w4;
                w4[0] = (short)f2bf(r0[k]);
                w4[1] = (short)f2bf(r1[k]);
                w4[2] = (short)f2bf(r2[k]);
                w4[3] = (short)f2bf(r3[k]);
                *(bf16x4*)&xs[nq * 4 + k][cs] = w4;
            }
        }
    }
    __syncthreads();

    f32x4 acc[5][2];
#pragma unroll
    for (int j = 0; j < 5; ++j) {
        f32x4 b4 = *(const f32x4*)&Bias[(w * 5 + j) * 16 + quad * 4];
        acc[j][0] = b4; acc[j][1] = b4;
    }

#pragma unroll
    for (int s = 0; s < 8; ++s) {
        bf16x8 Af[5], Bf[2];
#pragma unroll
        for (int j = 0; j < 5; ++j)
            Af[j] = *(const bf16x8*)&Wb[((w * 5 + j) * 16 + lc) * 256 + s * 32 + quad * 8];
#pragma unroll
        for (int nt = 0; nt < 2; ++nt) {
            int pos = nt * 16 + lc;
            int col = (s * 32 + quad * 8) ^ (((pos >> 2) & 3) << 3);
            Bf[nt] = *(const bf16x8*)&xs[pos][col];
        }
#pragma unroll
        for (int j = 0; j < 5; ++j)
#pragma unroll
            for (int nt = 0; nt < 2; ++nt)
                acc[j][nt] = __builtin_amdgcn_mfma_f32_16x16x32_bf16(Af[j], Bf[nt], acc[j][nt], 0, 0, 0);
    }

    // epilogue: D[oc=quad*4+i][pos=lc]
#pragma unroll
    for (int j = 0; j < 5; ++j) {
        int ot = w * 5 + j;
#pragma unroll
        for (int nt = 0; nt < 2; ++nt) {
            if (ot < 4) {   // q / k: [B][N][32]
                bf16x4 pk;
#pragma unroll
                for (int i = 0; i < 4; ++i) pk[i] = (short)f2bf(acc[j][nt][i]);
                unsigned short* bas = (ot < 2 ? qT : kT);
                int ocl = (ot & 1) * 16 + quad * 4;
                *(bf16x4*)&bas[((size_t)(b * NN + n0 + nt * 16 + lc)) * CQ + ocl] = pk;
            } else {        // v -> LDS transpose buffer [ch][pos]
#pragma unroll
                for (int i = 0; i < 4; ++i)
                    vs[(ot - 4) * 16 + quad * 4 + i][nt * 16 + lc] = f2bf(acc[j][nt][i]);
            }
        }
    }
    __syncthreads();

    // tiled V store: 16B per lane, 1KB contiguous per wave-pass
    const int mt = n0 >> 6, hb = (n0 >> 5) & 1;
    unsigned short* vt = ws + VT_OFF + ((size_t)(b * 64 + mt) * 16) * 1024 + hb * 512;
#pragma unroll
    for (int p = 0; p < 4; ++p) {
        int ci = p * 256 + t;
        int ct = ci >> 6, g = (ci >> 4) & 3, lcp = ci & 15;
        bf16x8 chunk = *(const bf16x8*)&vs[ct * 16 + lcp][g * 8];
        *(bf16x8*)&vt[(size_t)ct * 1024 + g * 128 + lcp * 8] = chunk;
    }
}

// ---------------------------------------------------------------------------
// MFMA flash attention, no max-subtraction, TK=128, 32 tiles.
// EXACT R4 kernel (47.2 us verified): grid 256 (XCD-swizzled), 1024 thr =
// 16 waves = 4/SIMD, checkerboard roles (8 QK + 8 PV, 2+2 per SIMD),
// ring-2 Ps, 1 barrier/tile, V half-tile register double-buffer.
// ---------------------------------------------------------------------------
__global__ __launch_bounds__(1024, 4) void attn_kernel(
    const float* __restrict__ x, const unsigned short* __restrict__ ws,
    const float* __restrict__ gamma, float* __restrict__ out)
{
    __shared__ __align__(16) unsigned short Ps[2][4][4][512];  // 32 KB
    __shared__ __align__(16) float lSpart[2][64];

    const int t = threadIdx.x;
    const int w = t >> 6, l = t & 63, quad = l >> 4, lc = l & 15;
    const int id = blockIdx.x, xcd = id & 7;
    const int b = xcd >> 1;
    const int n0 = (((id >> 3) << 1) | (xcd & 1)) * 64;
    const int role = (w + (w >> 2)) & 1;            // 0 = QK, 1 = PV (checkerboard)
    const int r = (w >> 2) * 2 + ((w & 3) >> 1);    // 0..7 within role

    const unsigned short* qT = ws + QT_OFF;
    const unsigned short* kb = ws + KT_OFF + (size_t)b * NN * CQ;
    const unsigned short* vbase = ws + VT_OFF + ((size_t)b << 20);

    if (role == 0) {
        // ============ QK / softmax producer wave (qg = r&3, kh = r>>2) =====
        const int qg = r & 3, kh = r >> 2;
        // Q as B-frag for S^T = K.Q^T: B[k=c=quad*8+j][n=qrow=lc]
        const bf16x8 bqf =
            *(const bf16x8*)&qT[((size_t)(b * NN + n0 + qg * 16 + lc)) * CQ + quad * 8];
        const f32x4 z = {0.f, 0.f, 0.f, 0.f};

        bf16x8 kA[4], kB[4];   // 4 x 16-key subtiles of this wave's 64-key half
        auto loadK = [&](bf16x8* kr, int tt) {
            int m0 = (tt & 31) * 128 + kh * 64;
#pragma unroll
            for (int j = 0; j < 4; ++j)
                kr[j] = *(const bf16x8*)&kb[(size_t)(m0 + j * 16 + lc) * CQ + quad * 8];
        };

        f32x4 sn[4];
        float lacc = 0.f;

        // exp + publish one 16-key subtile in A-frag tiled order (R0 exact).
        // key128 = kh*64 + j*16 + quad*4 + i -> ks = kh*2+(j>>1),
        // dest lane' = ((2j+(quad>>1))&3)*16 + lc, elem = (quad&1)*4 + i.
        auto expj = [&](int pp, int j) {
            bf16x4 pk;
#pragma unroll
            for (int i = 0; i < 4; ++i) {
                float p = __expf(sn[j][i]);
                lacc += p;
                pk[i] = (short)f2bf(p);
            }
            int ks = kh * 2 + (j >> 1);
            int lanep = ((2 * j + (quad >> 1)) & 3) * 16 + lc;
            *(bf16x4*)&Ps[pp][qg][ks][lanep * 8 + (quad & 1) * 4] = pk;
        };

        auto qkbody = [&](int tt, bf16x8* kUse, bf16x8* kNext) {
#pragma unroll
            for (int j = 0; j < 4; ++j)
                sn[j] = __builtin_amdgcn_mfma_f32_16x16x32_bf16(kUse[j], bqf, z, 0, 0, 0);
            loadK(kNext, tt + 2);
#pragma unroll
            for (int j = 0; j < 4; ++j) expj((tt + 1) & 1, j);
            LDS_BARRIER();
        };

        // prologue: S(0) -> exp -> Ps[0]; prefetch K(1)
        loadK(kA, 0);
#pragma unroll
        for (int j = 0; j < 4; ++j)
            sn[j] = __builtin_amdgcn_mfma_f32_16x16x32_bf16(kA[j], bqf, z, 0, 0, 0);
        loadK(kA, 1);
#pragma unroll
        for (int j = 0; j < 4; ++j) expj(0, j);
        LDS_BARRIER();                               // barrier #1

        for (int it = 0; it < 15; ++it) {
            qkbody(2 * it,     kA, kB);              // S(tt+1), prefetch K(tt+2)
            qkbody(2 * it + 1, kB, kA);
        }
        qkbody(30, kA, kB);                          // barriers #2..#32

        // l publish: reduce quads, store per key-half
        lacc += __shfl_xor(lacc, 16);
        lacc += __shfl_xor(lacc, 32);
        if (quad == 0) lSpart[kh][qg * 16 + lc] = lacc;
        LDS_BARRIER();                               // barrier #33
    } else {
        // ============ PV consumer wave (channels rv*32..+31) ===============
        const int rv = r;

        f32x4 acc[4][2];   // [qsub][ctile]
#pragma unroll
        for (int i = 0; i < 4; ++i)
#pragma unroll
            for (int j = 0; j < 2; ++j) acc[i][j] = (f32x4){0.f, 0.f, 0.f, 0.f};

        // V frags: half-tile double buffer, refills in flight across barriers
        // (vmcnt not drained by LDS_BARRIER).
        bf16x8 va[2][2], vb2[2][2];   // [c][kk]
        auto loadVhalf = [&](bf16x8 (*vr)[2], int tt, int half) {
            int m = (tt & 31) * 2 + half;
#pragma unroll
            for (int c = 0; c < 2; ++c) {
                int ct = rv * 2 + c;
#pragma unroll
                for (int kk = 0; kk < 2; ++kk)
                    vr[c][kk] = *(const bf16x8*)&vbase[((size_t)m * 16 + ct) * 1024 + kk * 512 + l * 8];
            }
        };

        auto pvks = [&](int pp, int ks, const bf16x8& v0, const bf16x8& v1) {
            bf16x8 ap[4];
#pragma unroll
            for (int qs = 0; qs < 4; ++qs)
                ap[qs] = *(const bf16x8*)&Ps[pp][qs][ks][l * 8];   // linear b128
            __builtin_amdgcn_s_setprio(1);
#pragma unroll
            for (int qs = 0; qs < 4; ++qs) {
                acc[qs][0] = __builtin_amdgcn_mfma_f32_16x16x32_bf16(ap[qs], v0, acc[qs][0], 0, 0, 0);
                acc[qs][1] = __builtin_amdgcn_mfma_f32_16x16x32_bf16(ap[qs], v1, acc[qs][1], 0, 0, 0);
            }
            __builtin_amdgcn_s_setprio(0);
        };

        // prologue: stage V(0) both halves
        loadVhalf(va, 0, 0);
        loadVhalf(vb2, 0, 1);
        LDS_BARRIER();                               // barrier #1

        for (int tt = 0; tt < 31; ++tt) {
            int pp = tt & 1;
            pvks(pp, 0, va[0][0], va[1][0]);
            pvks(pp, 1, va[0][1], va[1][1]);
            loadVhalf(va, tt + 1, 0);                // refill ks 0-1 of next tile
            pvks(pp, 2, vb2[0][0], vb2[1][0]);
            pvks(pp, 3, vb2[0][1], vb2[1][1]);
            loadVhalf(vb2, tt + 1, 1);               // refill ks 2-3 of next tile
            LDS_BARRIER();                           // barriers #2..#32
        }
        // tail: tile 31 from Ps[1] (loads issued at tt=30)
        pvks(1, 0, va[0][0], va[1][0]);
        pvks(1, 1, va[0][1], va[1][1]);
        pvks(1, 2, vb2[0][0], vb2[1][0]);
        pvks(1, 3, vb2[0][1], vb2[1][1]);
        LDS_BARRIER();                               // barrier #33 (lS ready)

        // epilogue: out = gamma * acc / l + x
        const float g = gamma[0];
#pragma unroll
        for (int qs = 0; qs < 4; ++qs) {
            f32x4 l0 = *(const f32x4*)&lSpart[0][qs * 16 + quad * 4];
            f32x4 l1 = *(const f32x4*)&lSpart[1][qs * 16 + quad * 4];
            f32x4 rl;
#pragma unroll
            for (int i = 0; i < 4; ++i) rl[i] = 1.f / (l0[i] + l1[i]);
#pragma unroll
            for (int c2 = 0; c2 < 2; ++c2) {
                int c = rv * 32 + c2 * 16 + lc;
                size_t base = ((size_t)(b * CC + c)) * NN + n0 + qs * 16 + quad * 4;
                f32x4 xr = *(const f32x4*)&x[base];
                f32x4 o;
#pragma unroll
                for (int i = 0; i < 4; ++i) o[i] = g * acc[qs][c2][i] * rl[i] + xr[i];
                *(f32x4*)&out[base] = o;
            }
        }
    }
}

extern "C" void kernel_launch(void* const* d_in, const int* in_sizes, int n_in,
                              void* d_out, int out_size, void* d_ws, size_t ws_size,
                              hipStream_t stream) {
    const float* x     = (const float*)d_in[0];
    const float* wq    = (const float*)d_in[1];
    const float* bq    = (const float*)d_in[2];
    const float* wk    = (const float*)d_in[3];
    const float* bk    = (const float*)d_in[4];
    const float* wv    = (const float*)d_in[5];
    const float* bv    = (const float*)d_in[6];
    const float* gamma = (const float*)d_in[7];
    float* out = (float*)d_out;
    unsigned short* ws = (unsigned short*)d_ws;   // ~10.7 MB used

    prepw_kernel<<<320, 256, 0, stream>>>(wq, bq, wk, bk, wv, bv, ws);
    dim3 g1(NN / 32, BB);
    // MEASUREMENT: qkv launched 3x (idempotent). wall = base + 2*qkv_dur,
    // resolving qkv's true cost at +-0.1 us before committing to a rewrite.
    qkv_kernel<<<g1, 256, 0, stream>>>(x, ws);
    qkv_kernel<<<g1, 256, 0, stream>>>(x, ws);
    qkv_kernel<<<g1, 256, 0, stream>>>(x, ws);
    attn_kernel<<<256, 1024, 0, stream>>>(x, ws, gamma, out);
}

// Round 11
// 136.398 us; speedup vs baseline: 1.2088x; 1.2088x over previous
//
#include <hip/hip_runtime.h>

// Problem constants (fixed by setup_inputs)
#define BB 4
#define CC 256
#define CQ 32
#define NN 4096   // H*W

// ws layout (bf16 element offsets)
#define QT_OFF 0
#define KT_OFF (BB*NN*CQ)                 //  524288
#define VT_OFF (2*BB*NN*CQ)               // 1048576 : tiled V, BB*64*16*1024
#define WB_OFF (VT_OFF + BB*CC*NN)        // 5242880 : bf16 W [320][256]
#define BIAS_OFF (WB_OFF + 320*256)       // 5324800 : fp32 bias[320] (16B-aligned)

// Barrier with LDS-only drain: does NOT wait vmcnt, so register prefetch
// loads (V/K fragments) stay in flight across the barrier. __syncthreads()
// would emit s_waitcnt vmcnt(0) and serialize every iteration on L2 latency.
#define LDS_BARRIER() asm volatile("s_waitcnt lgkmcnt(0)\ns_barrier" ::: "memory")

typedef __attribute__((ext_vector_type(8))) short bf16x8;
typedef __attribute__((ext_vector_type(4))) short bf16x4;
typedef __attribute__((ext_vector_type(4))) float f32x4;

__device__ inline unsigned short f2bf(float f) {
    unsigned int u = __float_as_uint(f);
    u += 0x7fffu + ((u >> 16) & 1u);   // round-to-nearest-even
    return (unsigned short)(u >> 16);
}

// ---------------------------------------------------------------------------
// prepW: pack wq/wk/wv into bf16 Wb[320][256] (rows 0-31 q, 32-63 k, 64-319 v)
// and biases into fp32 Bias[320]. Grid 320 x 256.  (R4-exact)
// ---------------------------------------------------------------------------
__global__ __launch_bounds__(256) void prepw_kernel(
    const float* __restrict__ wq, const float* __restrict__ bq,
    const float* __restrict__ wk, const float* __restrict__ bk,
    const float* __restrict__ wv, const float* __restrict__ bv,
    unsigned short* __restrict__ ws)
{
    unsigned short* Wb = ws + WB_OFF;
    float* Bias = (float*)(ws + BIAS_OFF);
    int idx = blockIdx.x * 256 + threadIdx.x;
    if (idx < 320 * 256) {
        int row = idx >> 8, col = idx & 255;
        float v = row < 32 ? wq[row * 256 + col]
                : row < 64 ? wk[(row - 32) * 256 + col]
                           : wv[(row - 64) * 256 + col];
        Wb[idx] = f2bf(v);
    }
    if (idx < 320)
        Bias[idx] = idx < 32 ? bq[idx] : idx < 64 ? bk[idx - 32] : bv[idx - 64];
}

// ---------------------------------------------------------------------------
// Fused x-transpose + QKV MFMA GEMM: [320 oc] x [256 c] x [64 pos].
// R11: measured qkv = 14.1 us (R10 3x-launch delta), ~3x roofline; R9's
// controlled experiment (Af reads doubled -> +9.5 us) pins the cost on the
// per-wave W-fragment L2 gathers. W-traffic ~ total_MFMA / (pos per wave):
// R4 had nt=2 (80 MB). This version: 64-pos tiles, grid (NN/64,B)=256 blocks
// x 256 thr, wave g owns 5 oc-frags x nt=4 pos-frags (acc[5][4], 160 MFMA)
// -> W traffic halved to 40 MB. At 1 wave/SIMD the 20-MFMA cluster per
// s-step (~390 cyc) self-covers its 9 L2 loads (~200 cyc): ILP replaces TLP.
// Staging/swizzle/epilogue/V-tile patterns are the R4-proven ones extended
// to 64 pos. LDS 70.6 KB static (>64 KB OK: R8 ran 74.7 KB).
// ---------------------------------------------------------------------------
__global__ __launch_bounds__(256, 1) void qkv_kernel(
    const float* __restrict__ x, unsigned short* __restrict__ ws)
{
    __shared__ __align__(16) unsigned short xs[64][264];   // [pos][ch^swz] 33.8 KB
    __shared__ __align__(16) unsigned short vs[256][72];   // [ch][pos+pad] 36.9 KB
    const int t = threadIdx.x;
    const int w = t >> 6, l = t & 63, quad = l >> 4, lc = l & 15;
    const int b = blockIdx.y, n0 = blockIdx.x * 64;

    unsigned short* qT = ws + QT_OFF;
    unsigned short* kT = ws + KT_OFF;
    const unsigned short* Wb = ws + WB_OFF;
    const float* Bias = (const float*)(ws + BIAS_OFF);

    // stage x tile: fp32 [256 ch][64 pos] -> bf16 xs[pos][ch ^ swz]
    // thread: pos-quad nq = t&15 (4 pos), row-group rg = t>>4 (4 ch) x 4 u
    const float* xb = x + (size_t)(b * CC) * NN + n0;
    {
        const int nq = t & 15, swz = (nq & 3) << 3;
#pragma unroll
        for (int u = 0; u < 4; ++u) {
            const int c0 = (t >> 4) * 4 + u * 64;
            f32x4 r0 = *(const f32x4*)&xb[(size_t)(c0 + 0) * NN + nq * 4];
            f32x4 r1 = *(const f32x4*)&xb[(size_t)(c0 + 1) * NN + nq * 4];
            f32x4 r2 = *(const f32x4*)&xb[(size_t)(c0 + 2) * NN + nq * 4];
            f32x4 r3 = *(const f32x4*)&xb[(size_t)(c0 + 3) * NN + nq * 4];
            const int cs = c0 ^ swz;   // c0 mult of 4, swz bits 3-4 -> 8B aligned
#pragma unroll
            for (int k = 0; k < 4; ++k) {
                bf16x4 w4;
                w4[0] = (short)f2bf(r0[k]);
                w4[1] = (short)f2bf(r1[k]);
                w4[2] = (short)f2bf(r2[k]);
                w4[3] = (short)f2bf(r3[k]);
                *(bf16x4*)&xs[nq * 4 + k][cs] = w4;
            }
        }
    }
    __syncthreads();

    // wave w: oc-frags w*5..w*5+4, ALL 4 pos-frags (nt=4 -> W reads amortized)
    f32x4 acc[5][4];
#pragma unroll
    for (int j = 0; j < 5; ++j) {
        f32x4 b4 = *(const f32x4*)&Bias[(w * 5 + j) * 16 + quad * 4];
#pragma unroll
        for (int nt = 0; nt < 4; ++nt) acc[j][nt] = b4;
    }

#pragma unroll
    for (int s = 0; s < 8; ++s) {
        bf16x8 Af[5], Bf[4];
#pragma unroll
        for (int j = 0; j < 5; ++j)
            Af[j] = *(const bf16x8*)&Wb[((w * 5 + j) * 16 + lc) * 256 + s * 32 + quad * 8];
#pragma unroll
        for (int nt = 0; nt < 4; ++nt) {
            int pos = nt * 16 + lc;
            int col = (s * 32 + quad * 8) ^ (((pos >> 2) & 3) << 3);
            Bf[nt] = *(const bf16x8*)&xs[pos][col];
        }
#pragma unroll
        for (int j = 0; j < 5; ++j)
#pragma unroll
            for (int nt = 0; nt < 4; ++nt)
                acc[j][nt] = __builtin_amdgcn_mfma_f32_16x16x32_bf16(Af[j], Bf[nt], acc[j][nt], 0, 0, 0);
    }

    // epilogue: D[oc=quad*4+i][pos=nt*16+lc]
#pragma unroll
    for (int j = 0; j < 5; ++j) {
        int ot = w * 5 + j;
#pragma unroll
        for (int nt = 0; nt < 4; ++nt) {
            if (ot < 4) {   // q / k: [B][N][32]
                bf16x4 pk;
#pragma unroll
                for (int i = 0; i < 4; ++i) pk[i] = (short)f2bf(acc[j][nt][i]);
                unsigned short* bas = (ot < 2 ? qT : kT);
                int ocl = (ot & 1) * 16 + quad * 4;
                *(bf16x4*)&bas[((size_t)(b * NN + n0 + nt * 16 + lc)) * CQ + ocl] = pk;
            } else {        // v -> LDS transpose buffer [ch][pos]
#pragma unroll
                for (int i = 0; i < 4; ++i)
                    vs[(ot - 4) * 16 + quad * 4 + i][nt * 16 + lc] = f2bf(acc[j][nt][i]);
            }
        }
    }
    __syncthreads();

    // tiled V store: 16B per lane, 1KB contiguous per ct-tile.
    // Tile (b, mt=n0>>6): [16 ct][2 hb][4 g2][16 lcp][8 pos] -- both 32-pos
    // halves (hb) produced by this block. 2048 chunks, 8/thread.
    const int mt = n0 >> 6;
    unsigned short* vt = ws + VT_OFF + ((size_t)(b * 64 + mt) * 16) * 1024;
#pragma unroll
    for (int p = 0; p < 8; ++p) {
        int ci = p * 256 + t;                 // ci = ct*128 + g2*16 + lcp
        int ct = ci >> 7, g2 = (ci >> 4) & 7, lcp = ci & 15;
        bf16x8 chunk = *(const bf16x8*)&vs[ct * 16 + lcp][g2 * 8];
        *(bf16x8*)&vt[(size_t)ct * 1024 + (g2 >> 2) * 512 + (g2 & 3) * 128 + lcp * 8] = chunk;
    }
}

// ---------------------------------------------------------------------------
// MFMA flash attention, no max-subtraction, TK=128, 32 tiles.
// EXACT R4 kernel (47.2 us verified): grid 256 (XCD-swizzled), 1024 thr =
// 16 waves = 4/SIMD, checkerboard roles (8 QK + 8 PV, 2+2 per SIMD),
// ring-2 Ps, 1 barrier/tile, V half-tile register double-buffer.
// ---------------------------------------------------------------------------
__global__ __launch_bounds__(1024, 4) void attn_kernel(
    const float* __restrict__ x, const unsigned short* __restrict__ ws,
    const float* __restrict__ gamma, float* __restrict__ out)
{
    __shared__ __align__(16) unsigned short Ps[2][4][4][512];  // 32 KB
    __shared__ __align__(16) float lSpart[2][64];

    const int t = threadIdx.x;
    const int w = t >> 6, l = t & 63, quad = l >> 4, lc = l & 15;
    const int id = blockIdx.x, xcd = id & 7;
    const int b = xcd >> 1;
    const int n0 = (((id >> 3) << 1) | (xcd & 1)) * 64;
    const int role = (w + (w >> 2)) & 1;            // 0 = QK, 1 = PV (checkerboard)
    const int r = (w >> 2) * 2 + ((w & 3) >> 1);    // 0..7 within role

    const unsigned short* qT = ws + QT_OFF;
    const unsigned short* kb = ws + KT_OFF + (size_t)b * NN * CQ;
    const unsigned short* vbase = ws + VT_OFF + ((size_t)b << 20);

    if (role == 0) {
        // ============ QK / softmax producer wave (qg = r&3, kh = r>>2) =====
        const int qg = r & 3, kh = r >> 2;
        // Q as B-frag for S^T = K.Q^T: B[k=c=quad*8+j][n=qrow=lc]
        const bf16x8 bqf =
            *(const bf16x8*)&qT[((size_t)(b * NN + n0 + qg * 16 + lc)) * CQ + quad * 8];
        const f32x4 z = {0.f, 0.f, 0.f, 0.f};

        bf16x8 kA[4], kB[4];   // 4 x 16-key subtiles of this wave's 64-key half
        auto loadK = [&](bf16x8* kr, int tt) {
            int m0 = (tt & 31) * 128 + kh * 64;
#pragma unroll
            for (int j = 0; j < 4; ++j)
                kr[j] = *(const bf16x8*)&kb[(size_t)(m0 + j * 16 + lc) * CQ + quad * 8];
        };

        f32x4 sn[4];
        float lacc = 0.f;

        // exp + publish one 16-key subtile in A-frag tiled order (R0 exact).
        // key128 = kh*64 + j*16 + quad*4 + i -> ks = kh*2+(j>>1),
        // dest lane' = ((2j+(quad>>1))&3)*16 + lc, elem = (quad&1)*4 + i.
        auto expj = [&](int pp, int j) {
            bf16x4 pk;
#pragma unroll
            for (int i = 0; i < 4; ++i) {
                float p = __expf(sn[j][i]);
                lacc += p;
                pk[i] = (short)f2bf(p);
            }
            int ks = kh * 2 + (j >> 1);
            int lanep = ((2 * j + (quad >> 1)) & 3) * 16 + lc;
            *(bf16x4*)&Ps[pp][qg][ks][lanep * 8 + (quad & 1) * 4] = pk;
        };

        auto qkbody = [&](int tt, bf16x8* kUse, bf16x8* kNext) {
#pragma unroll
            for (int j = 0; j < 4; ++j)
                sn[j] = __builtin_amdgcn_mfma_f32_16x16x32_bf16(kUse[j], bqf, z, 0, 0, 0);
            loadK(kNext, tt + 2);
#pragma unroll
            for (int j = 0; j < 4; ++j) expj((tt + 1) & 1, j);
            LDS_BARRIER();
        };

        // prologue: S(0) -> exp -> Ps[0]; prefetch K(1)
        loadK(kA, 0);
#pragma unroll
        for (int j = 0; j < 4; ++j)
            sn[j] = __builtin_amdgcn_mfma_f32_16x16x32_bf16(kA[j], bqf, z, 0, 0, 0);
        loadK(kA, 1);
#pragma unroll
        for (int j = 0; j < 4; ++j) expj(0, j);
        LDS_BARRIER();                               // barrier #1

        for (int it = 0; it < 15; ++it) {
            qkbody(2 * it,     kA, kB);              // S(tt+1), prefetch K(tt+2)
            qkbody(2 * it + 1, kB, kA);
        }
        qkbody(30, kA, kB);                          // barriers #2..#32

        // l publish: reduce quads, store per key-half
        lacc += __shfl_xor(lacc, 16);
        lacc += __shfl_xor(lacc, 32);
        if (quad == 0) lSpart[kh][qg * 16 + lc] = lacc;
        LDS_BARRIER();                               // barrier #33
    } else {
        // ============ PV consumer wave (channels rv*32..+31) ===============
        const int rv = r;

        f32x4 acc[4][2];   // [qsub][ctile]
#pragma unroll
        for (int i = 0; i < 4; ++i)
#pragma unroll
            for (int j = 0; j < 2; ++j) acc[i][j] = (f32x4){0.f, 0.f, 0.f, 0.f};

        // V frags: half-tile double buffer, refills in flight across barriers
        // (vmcnt not drained by LDS_BARRIER).
        bf16x8 va[2][2], vb2[2][2];   // [c][kk]
        auto loadVhalf = [&](bf16x8 (*vr)[2], int tt, int half) {
            int m = (tt & 31) * 2 + half;
#pragma unroll
            for (int c = 0; c < 2; ++c) {
                int ct = rv * 2 + c;
#pragma unroll
                for (int kk = 0; kk < 2; ++kk)
                    vr[c][kk] = *(const bf16x8*)&vbase[((size_t)m * 16 + ct) * 1024 + kk * 512 + l * 8];
            }
        };

        auto pvks = [&](int pp, int ks, const bf16x8& v0, const bf16x8& v1) {
            bf16x8 ap[4];
#pragma unroll
            for (int qs = 0; qs < 4; ++qs)
                ap[qs] = *(const bf16x8*)&Ps[pp][qs][ks][l * 8];   // linear b128
            __builtin_amdgcn_s_setprio(1);
#pragma unroll
            for (int qs = 0; qs < 4; ++qs) {
                acc[qs][0] = __builtin_amdgcn_mfma_f32_16x16x32_bf16(ap[qs], v0, acc[qs][0], 0, 0, 0);
                acc[qs][1] = __builtin_amdgcn_mfma_f32_16x16x32_bf16(ap[qs], v1, acc[qs][1], 0, 0, 0);
            }
            __builtin_amdgcn_s_setprio(0);
        };

        // prologue: stage V(0) both halves
        loadVhalf(va, 0, 0);
        loadVhalf(vb2, 0, 1);
        LDS_BARRIER();                               // barrier #1

        for (int tt = 0; tt < 31; ++tt) {
            int pp = tt & 1;
            pvks(pp, 0, va[0][0], va[1][0]);
            pvks(pp, 1, va[0][1], va[1][1]);
            loadVhalf(va, tt + 1, 0);                // refill ks 0-1 of next tile
            pvks(pp, 2, vb2[0][0], vb2[1][0]);
            pvks(pp, 3, vb2[0][1], vb2[1][1]);
            loadVhalf(vb2, tt + 1, 1);               // refill ks 2-3 of next tile
            LDS_BARRIER();                           // barriers #2..#32
        }
        // tail: tile 31 from Ps[1] (loads issued at tt=30)
        pvks(1, 0, va[0][0], va[1][0]);
        pvks(1, 1, va[0][1], va[1][1]);
        pvks(1, 2, vb2[0][0], vb2[1][0]);
        pvks(1, 3, vb2[0][1], vb2[1][1]);
        LDS_BARRIER();                               // barrier #33 (lS ready)

        // epilogue: out = gamma * acc / l + x
        const float g = gamma[0];
#pragma unroll
        for (int qs = 0; qs < 4; ++qs) {
            f32x4 l0 = *(const f32x4*)&lSpart[0][qs * 16 + quad * 4];
            f32x4 l1 = *(const f32x4*)&lSpart[1][qs * 16 + quad * 4];
            f32x4 rl;
#pragma unroll
            for (int i = 0; i < 4; ++i) rl[i] = 1.f / (l0[i] + l1[i]);
#pragma unroll
            for (int c2 = 0; c2 < 2; ++c2) {
                int c = rv * 32 + c2 * 16 + lc;
                size_t base = ((size_t)(b * CC + c)) * NN + n0 + qs * 16 + quad * 4;
                f32x4 xr = *(const f32x4*)&x[base];
                f32x4 o;
#pragma unroll
                for (int i = 0; i < 4; ++i) o[i] = g * acc[qs][c2][i] * rl[i] + xr[i];
                *(f32x4*)&out[base] = o;
            }
        }
    }
}

extern "C" void kernel_launch(void* const* d_in, const int* in_sizes, int n_in,
                              void* d_out, int out_size, void* d_ws, size_t ws_size,
                              hipStream_t stream) {
    const float* x     = (const float*)d_in[0];
    const float* wq    = (const float*)d_in[1];
    const float* bq    = (const float*)d_in[2];
    const float* wk    = (const float*)d_in[3];
    const float* bk    = (const float*)d_in[4];
    const float* wv    = (const float*)d_in[5];
    const float* bv    = (const float*)d_in[6];
    const float* gamma = (const float*)d_in[7];
    float* out = (float*)d_out;
    unsigned short* ws = (unsigned short*)d_ws;   // ~10.7 MB used

    prepw_kernel<<<320, 256, 0, stream>>>(wq, bq, wk, bk, wv, bv, ws);
    dim3 g1(NN / 64, BB);
    qkv_kernel<<<g1, 256, 0, stream>>>(x, ws);
    attn_kernel<<<256, 1024, 0, stream>>>(x, ws, gamma, out);
}